// Round 4
// baseline (580.063 us; speedup 1.0000x reference)
//
#include <hip/hip_runtime.h>

typedef unsigned int u32;
typedef unsigned long long u64;

#define N_IMG 32
#define NA 67200
#define KTOP 1024
#define IM_F 1280.0f
#define NBIN 65536          // 16-bit radix of u>>14 (u <= 0x3F800000 -> bin <= 65024)
#define CANDB_CAP 16384

// Correctly-rounded f32 exp via double (matches any faithful reference exp
// at virtually every point).
__device__ __forceinline__ float cr_expf(float x) { return (float)exp((double)x); }

__device__ __forceinline__ u64 readlane64(u64 v, int lane) {
    u32 lo = (u32)__builtin_amdgcn_readlane((int)(u32)v, lane);
    u32 hi = (u32)__builtin_amdgcn_readlane((int)(u32)(v >> 32), lane);
    return ((u64)hi << 32) | (u64)lo;
}

// ---------------- K1: fused softmax score + global histogram ----------------
__global__ __launch_bounds__(256) void score_hist_kernel(const float2* __restrict__ conf,
                                                         float* __restrict__ scores,
                                                         u32* __restrict__ ghist) {
    int id = blockIdx.x * 256 + threadIdx.x;
    if (id >= N_IMG * NA) return;
    int n = id / NA;
    float2 c = conf[id];
    float m  = fmaxf(c.x, c.y);
    float e0 = cr_expf(c.x - m);   // one of these is exp(0)=1 exactly
    float e1 = cr_expf(c.y - m);
    float s  = e1 / (e0 + e1);
    scores[id] = s;
    u32 u = __float_as_uint(s);
    atomicAdd(&ghist[n * NBIN + (u >> 14)], 1u);
}

// ---------------- K2: per-image rank-1024 bin via top-down suffix scan -------
// Finds crossing bin B: GE(B) >= KTOP > GT(B); R = KTOP - GT(B).
__global__ __launch_bounds__(1024) void thresh_kernel(const u32* __restrict__ ghist,
                                                      u32* __restrict__ thr) {
    const int n = blockIdx.x, tid = threadIdx.x;
    __shared__ u32 sA[1024], sB[1024];
    __shared__ int found;
    __shared__ u32 res_b, res_r;
    if (tid == 0) found = 0;
    __syncthreads();

    u32 above = 0;   // count of values in bins strictly above current chunk
    #pragma unroll 1
    for (int c = 0; c < NBIN / 1024; ++c) {
        const int lo = NBIN - (c + 1) * 1024;
        sA[tid] = ghist[n * NBIN + lo + tid];
        __syncthreads();
        u32 *src = sA, *dst = sB;
        for (int d = 1; d < 1024; d <<= 1) {
            dst[tid] = src[tid] + ((tid + d < 1024) ? src[tid + d] : 0u);
            __syncthreads();
            u32* t = src; src = dst; dst = t;
        }
        u32 GE = above + src[tid];                                  // >= bin lo+tid
        u32 GT = above + ((tid + 1 < 1024) ? src[tid + 1] : 0u);    // >  bin lo+tid
        if (GE >= KTOP && GT < KTOP) {          // unique crossing
            res_b = (u32)(lo + tid);
            res_r = KTOP - GT;
            found = 1;
        }
        above += src[0];
        __syncthreads();
        if (found) break;
    }
    if (tid == 0) { thr[2 * n] = res_b; thr[2 * n + 1] = res_r; }
}

// ---------------- K3: compact candidates (definite / boundary) ----------------
__global__ __launch_bounds__(256) void compact_kernel(const float* __restrict__ scores,
                                                      const u32* __restrict__ thr,
                                                      u64* __restrict__ candd, u32* __restrict__ cntd,
                                                      u64* __restrict__ candb, u32* __restrict__ cntb) {
    int id = blockIdx.x * 256 + threadIdx.x;
    if (id >= N_IMG * NA) return;
    int n = id / NA;
    int a = id - n * NA;
    u32 u = __float_as_uint(scores[id]);
    u32 B = thr[2 * n];
    u32 b = u >> 14;
    if (b > B) {
        u32 p = atomicAdd(&cntd[n], 1u);                 // provably < KTOP
        candd[(size_t)n * KTOP + p] = ((u64)u << 32) | (u32)(~(u32)a);
    } else if (b == B) {
        u32 p = atomicAdd(&cntb[n], 1u);
        if (p < CANDB_CAP)
            candb[(size_t)n * CANDB_CAP + p] = ((u64)u << 32) | (u32)(~(u32)a);
    }
}

// ---------------- K4: exact select (rank-count boundary) + bitonic sort -------
// key = (score_bits<<32)|~idx ; desc key == score desc, index asc (lax.top_k ties).
__global__ __launch_bounds__(1024) void select_kernel(const u64* __restrict__ candd,
                                                      const u32* __restrict__ cntd,
                                                      const u64* __restrict__ candb,
                                                      const u32* __restrict__ cntb,
                                                      u32* __restrict__ top_idx,
                                                      float* __restrict__ top_score) {
    const int n = blockIdx.x, tid = threadIdx.x;
    __shared__ u64 cand[KTOP];

    const int D = (int)cntd[n];          // == GT(B) < KTOP
    const int R = KTOP - D;              // to take from boundary bin
    if (tid < D) cand[tid] = candd[(size_t)n * KTOP + tid];

    const int E = min((int)cntb[n], CANDB_CAP);   // >= R by construction
    const u64* cb = candb + (size_t)n * CANDB_CAP;
    for (int t = tid; t < E; t += 1024) {
        u64 k = cb[t];
        int rank = 0;
        for (int j = 0; j < E; ++j) rank += (cb[j] > k);   // keys unique (idx distinct)
        if (rank < R) cand[D + rank] = k;
    }
    __syncthreads();

    // bitonic sort descending, 1024 elements
    for (int k = 2; k <= KTOP; k <<= 1) {
        for (int j = k >> 1; j > 0; j >>= 1) {
            int i = tid;
            int ixj = i ^ j;
            if (ixj > i) {
                u64 a_ = cand[i], b_ = cand[ixj];
                bool sw = ((i & k) == 0) ? (a_ < b_) : (a_ > b_);
                if (sw) { cand[i] = b_; cand[ixj] = a_; }
            }
            __syncthreads();
        }
    }

    u64 c = cand[tid];
    top_idx[n * KTOP + tid]   = ~(u32)(c & 0xFFFFFFFFull);
    top_score[n * KTOP + tid] = __uint_as_float((u32)(c >> 32));
}

// ---------------- K5: gather + decode boxes/landmarks ----------------
__global__ void decode_kernel(const float* __restrict__ loc, const float* __restrict__ landms,
                              const float* __restrict__ priors, const u32* __restrict__ top_idx,
                              const float* __restrict__ top_score, float* __restrict__ det) {
    int id = blockIdx.x * blockDim.x + threadIdx.x;
    if (id >= N_IMG * KTOP) return;
    int n = id >> 10;
    u32 a = top_idx[id];
    float4 p = *(const float4*)(priors + (size_t)a * 4);
    float4 l = *(const float4*)(loc + ((size_t)n * NA + a) * 4);

    float cx = p.x + l.x * 0.1f * p.z;
    float cy = p.y + l.y * 0.1f * p.w;
    float w  = p.z * cr_expf(l.z * 0.2f);
    float h  = p.w * cr_expf(l.w * 0.2f);

    float* o = det + (size_t)id * 15;
    o[0] = (cx - w * 0.5f) * IM_F;
    o[1] = (cy - h * 0.5f) * IM_F;
    o[2] = (cx + w * 0.5f) * IM_F;
    o[3] = (cy + h * 0.5f) * IM_F;
    o[4] = top_score[id];

    const float* mp = landms + ((size_t)n * NA + a) * 10;
    #pragma unroll
    for (int q = 0; q < 5; ++q) {
        o[5 + 2 * q]     = (p.x + mp[2 * q]     * 0.1f * p.z) * IM_F;
        o[5 + 2 * q + 1] = (p.y + mp[2 * q + 1] * 0.1f * p.w) * IM_F;
    }
}

// ---------------- K6: IoU suppression bitmask, wave-per-row + ballot ----------
__global__ __launch_bounds__(256) void mask_kernel(const float* __restrict__ det,
                                                   u64* __restrict__ mask) {
    const int n    = blockIdx.x >> 4;        // image
    const int sub  = blockIdx.x & 15;        // block within image
    const int wid  = threadIdx.x >> 6;       // wave in block
    const int lane = threadIdx.x & 63;
    const int q    = sub * 4 + wid;          // wave id within image, 0..63
    const int tid  = threadIdx.x;

    __shared__ float bx1[KTOP], by1[KTOP], bx2[KTOP], by2[KTOP], ba[KTOP];
    for (int j = tid; j < KTOP; j += 256) {
        const float* dr = det + ((size_t)n * KTOP + j) * 15;
        float x1 = dr[0], y1 = dr[1], x2 = dr[2], y2 = dr[3];
        bx1[j] = x1; by1[j] = y1; bx2[j] = x2; by2[j] = y2;
        ba[j] = fmaxf(x2 - x1, 0.f) * fmaxf(y2 - y1, 0.f);
    }
    __syncthreads();

    u64* mbase = mask + (size_t)n * KTOP * 16;
    #pragma unroll 1
    for (int k = 0; k < 16; ++k) {
        const int i = k * 64 + q;
        const float x1i = bx1[i], y1i = by1[i], x2i = bx2[i], y2i = by2[i], ai = ba[i];
        u64* orow = mbase + (size_t)i * 16;
        if (lane < k) orow[lane] = 0ull;               // zero low words
        #pragma unroll 1
        for (int w = k; w < 16; ++w) {
            const int j = w * 64 + lane;
            bool bit = false;
            if (j > i) {
                float xx1 = fmaxf(x1i, bx1[j]);
                float yy1 = fmaxf(y1i, by1[j]);
                float xx2 = fminf(x2i, bx2[j]);
                float yy2 = fminf(y2i, by2[j]);
                float inter = fmaxf(xx2 - xx1, 0.f) * fmaxf(yy2 - yy1, 0.f);
                float iou = inter / (ai + ba[j] - inter + 1e-9f);   // ref formula order
                bit = iou > 0.4f;
            }
            u64 m = __ballot(bit);
            if (lane == 0) orow[w] = m;
        }
    }
}

// ---------------- K7: LDS-staged sequential greedy NMS + fused masked output ----
__global__ __launch_bounds__(1024) void nms_out_kernel(const float* __restrict__ top_score,
                                                       const u64* __restrict__ mask,
                                                       const float* __restrict__ det,
                                                       float* __restrict__ out) {
    const int n = blockIdx.x;
    const int tid = threadIdx.x;
    __shared__ u64 lmask[512 * 16];   // 64 KB: one half of the 1024x1024-bit mask

    const u64* mbase = mask + (size_t)n * KTOP * 16;
    u64 myw = 0;
    if (tid < 64) {
        const int lane = tid;
        for (int g = 0; g < 16; ++g) {
            u64 b = __ballot(top_score[n * KTOP + g * 64 + lane] > 0.5f);
            if (lane == g) myw = b;
        }
    }

    #pragma unroll 1
    for (int half = 0; half < 2; ++half) {
        __syncthreads();   // protect lmask from previous half's readers
        #pragma unroll
        for (int k = 0; k < 8; ++k) {
            int idx = tid + k * 1024;
            lmask[idx] = mbase[(size_t)half * 8192 + idx];
        }
        __syncthreads();
        if (tid < 64) {
            const int lane = tid;
            for (int g = half * 8; g < half * 8 + 8; ++g) {
                u64 kw = readlane64(myw, g);   // group's current keep bits -> SGPR
                const int rbase = (g * 64 - half * 512) * 16;
                #pragma unroll 8
                for (int l = 0; l < 64; ++l) {
                    u64 row = lmask[rbase + l * 16 + (lane & 15)];
                    if ((kw >> l) & 1ull) {
                        kw &= ~readlane64(row, g);       // in-group forward suppress
                        if (lane < 16) myw &= ~row;      // global forward suppress
                    }
                }
            }
        }
    }
    __syncthreads();
    if (tid < 16) lmask[tid] = myw;   // publish keep bits (mask rows no longer needed)
    __syncthreads();

    // masked output write: 15360 floats per image, element-parallel (coalesced)
    const float* drow = det + (size_t)n * KTOP * 15;
    float* orow = out + (size_t)n * KTOP * 15;
    for (int e = tid; e < KTOP * 15; e += 1024) {
        int k = e / 15;
        float f = ((lmask[k >> 6] >> (k & 63)) & 1ull) ? 1.0f : 0.0f;
        orow[e] = drow[e] * f;
    }
}

extern "C" void kernel_launch(void* const* d_in, const int* in_sizes, int n_in,
                              void* d_out, int out_size, void* d_ws, size_t ws_size,
                              hipStream_t stream) {
    const float* loc    = (const float*)d_in[0];
    const float* conf   = (const float*)d_in[1];
    const float* landms = (const float*)d_in[2];
    const float* priors = (const float*)d_in[3];

    char* ws = (char*)d_ws;
    size_t off = 0;
    auto carve = [&](size_t bytes) { void* p = ws + off; off = (off + bytes + 255) & ~255ull; return p; };
    float* scores    = (float*)carve(sizeof(float) * (size_t)N_IMG * NA);
    u32*   top_idx   = (u32*)  carve(sizeof(u32)   * N_IMG * KTOP);
    float* top_score = (float*)carve(sizeof(float) * N_IMG * KTOP);
    float* det       = (float*)carve(sizeof(float) * N_IMG * KTOP * 15);
    u32*   ghist     = (u32*)  carve(sizeof(u32)   * (size_t)N_IMG * NBIN);   // 8 MB
    u64*   mask      = (u64*)ghist;   // alias: ghist dead before mask is written
    u64*   candd     = (u64*)  carve(sizeof(u64)   * N_IMG * KTOP);
    u64*   candb     = (u64*)  carve(sizeof(u64)   * (size_t)N_IMG * CANDB_CAP);
    u32*   cnts      = (u32*)  carve(256);          // cntd[32] | cntb[32]
    u32*   thr       = (u32*)  carve(sizeof(u32)   * N_IMG * 2);
    u32*   cntd = cnts, *cntb = cnts + 32;

    hipMemsetAsync(ghist, 0, sizeof(u32) * (size_t)N_IMG * NBIN, stream);
    hipMemsetAsync(cnts, 0, 256, stream);

    score_hist_kernel<<<(N_IMG * NA + 255) / 256, 256, 0, stream>>>((const float2*)conf, scores, ghist);
    thresh_kernel<<<N_IMG, 1024, 0, stream>>>(ghist, thr);
    compact_kernel<<<(N_IMG * NA + 255) / 256, 256, 0, stream>>>(scores, thr, candd, cntd, candb, cntb);
    select_kernel<<<N_IMG, 1024, 0, stream>>>(candd, cntd, candb, cntb, top_idx, top_score);
    decode_kernel<<<(N_IMG * KTOP + 255) / 256, 256, 0, stream>>>(loc, landms, priors, top_idx, top_score, det);
    mask_kernel<<<N_IMG * 16, 256, 0, stream>>>(det, mask);
    nms_out_kernel<<<N_IMG, 1024, 0, stream>>>(top_score, mask, det, (float*)d_out);
}

// Round 5
// 176.550 us; speedup vs baseline: 3.2855x; 3.2855x over previous
//
#include <hip/hip_runtime.h>

typedef unsigned int u32;
typedef unsigned long long u64;

#define N_IMG 32
#define NA 67200
#define KTOP 1024
#define IM_F 1280.0f
#define HBLK 8           // private-histogram blocks per image
#define HBIN 4096        // 12-bit radix of u>>18 (u <= 0x3F7FFFFF -> bin <= 4063)
#define HCHUNK 8400      // NA / HBLK
#define BCAP 6144        // boundary-bin candidate cap (expected ~670)

// Correctly-rounded f32 exp via double (matches any faithful reference exp
// at virtually every point).
__device__ __forceinline__ float cr_expf(float x) { return (float)exp((double)x); }

__device__ __forceinline__ u64 readlane64(u64 v, int lane) {
    u32 lo = (u32)__builtin_amdgcn_readlane((int)(u32)v, lane);
    u32 hi = (u32)__builtin_amdgcn_readlane((int)(u32)(v >> 32), lane);
    return ((u64)hi << 32) | (u64)lo;
}

// ---------------- K1: softmax face score, exact f32 chain ----------------
__global__ __launch_bounds__(256) void score_kernel(const float2* __restrict__ conf,
                                                    float* __restrict__ scores) {
    int id = blockIdx.x * 256 + threadIdx.x;
    if (id >= N_IMG * NA) return;
    float2 c = conf[id];
    float m  = fmaxf(c.x, c.y);
    float e0 = cr_expf(c.x - m);   // one of these is exp(0)=1 exactly
    float e1 = cr_expf(c.y - m);
    scores[id] = e1 / (e0 + e1);
}

// ---------------- K2: private per-block histograms (LDS only, no global atomics)
__global__ __launch_bounds__(256) void hist_kernel(const float* __restrict__ scores,
                                                   u32* __restrict__ hist) {
    const int n   = blockIdx.x >> 3;
    const int blk = blockIdx.x & 7;
    const int tid = threadIdx.x;
    __shared__ u32 h[HBIN];
    for (int i = tid; i < HBIN; i += 256) h[i] = 0;
    __syncthreads();
    const float* s = scores + (size_t)n * NA;
    const int base = blk * HCHUNK;
    for (int a = base + tid; a < base + HCHUNK; a += 256)
        atomicAdd(&h[__float_as_uint(s[a]) >> 18], 1u);
    __syncthreads();
    u32* out = hist + ((size_t)n * HBLK + blk) * HBIN;
    for (int i = tid; i < HBIN; i += 256) out[i] = h[i];
}

// ---------------- K3: per-image crossing bin via LDS suffix scan -------------
// B such that GE(B) >= KTOP > GT(B). Only B is needed downstream.
__global__ __launch_bounds__(1024) void thresh_kernel(const u32* __restrict__ hist,
                                                      u32* __restrict__ thr) {
    const int n = blockIdx.x, tid = threadIdx.x;
    __shared__ u32 sA[1024], sB[1024];
    __shared__ u32 res_b;
    const u32* hb = hist + (size_t)n * HBLK * HBIN;
    u32 h0 = 0, h1 = 0, h2 = 0, h3 = 0;
    #pragma unroll
    for (int blk = 0; blk < HBLK; ++blk) {
        const u32* p = hb + blk * HBIN + tid * 4;
        h0 += p[0]; h1 += p[1]; h2 += p[2]; h3 += p[3];
    }
    sA[tid] = h0 + h1 + h2 + h3;
    __syncthreads();
    u32 *src = sA, *dst = sB;
    for (int d = 1; d < 1024; d <<= 1) {
        dst[tid] = src[tid] + ((tid + d < 1024) ? src[tid + d] : 0u);
        __syncthreads();
        u32* t = src; src = dst; dst = t;
    }
    u32 GT3 = (tid + 1 < 1024) ? src[tid + 1] : 0u;   // sum over bins > 4*tid+3
    u32 GE3 = GT3 + h3;
    u32 GE2 = GE3 + h2;
    u32 GE1 = GE2 + h1;
    u32 GE0 = GE1 + h0;
    if (GE3 >= KTOP && GT3 < KTOP) res_b = 4u * tid + 3u;
    if (GE2 >= KTOP && GE3 < KTOP) res_b = 4u * tid + 2u;
    if (GE1 >= KTOP && GE2 < KTOP) res_b = 4u * tid + 1u;
    if (GE0 >= KTOP && GE1 < KTOP) res_b = 4u * tid + 0u;
    __syncthreads();
    if (tid == 0) thr[n] = res_b;
}

// ---------------- K4: exact select (LDS compact + rank-count) + bitonic sort --
// key = (score_bits<<32)|~idx ; desc key == score desc, index asc (lax.top_k ties).
// All counters in LDS -> no global atomic contention.
__global__ __launch_bounds__(1024) void select_kernel(const float* __restrict__ scores,
                                                      const u32* __restrict__ thr,
                                                      u32* __restrict__ top_idx,
                                                      float* __restrict__ top_score) {
    const int n = blockIdx.x, tid = threadIdx.x;
    __shared__ u64 cand[KTOP];      // 8 KB
    __shared__ u64 bkeys[BCAP];     // 48 KB
    __shared__ u32 cntd_s, cntb_s;
    if (tid == 0) { cntd_s = 0; cntb_s = 0; }
    __syncthreads();

    const u32 B = thr[n];
    const float* s = scores + (size_t)n * NA;
    for (int a = tid; a < NA; a += 1024) {
        u32 u = __float_as_uint(s[a]);
        u32 b = u >> 18;
        if (b > B) {
            u32 p = atomicAdd(&cntd_s, 1u);           // provably < KTOP
            cand[p] = ((u64)u << 32) | (u32)(~(u32)a);
        } else if (b == B) {
            u32 p = atomicAdd(&cntb_s, 1u);
            if (p < BCAP) bkeys[p] = ((u64)u << 32) | (u32)(~(u32)a);
        }
    }
    __syncthreads();

    const int D = (int)cntd_s;               // == GT(B) < KTOP
    const int R = KTOP - D;                  // take R largest boundary keys
    const int E = min((int)cntb_s, BCAP);    // >= R by construction (GE(B) >= KTOP)
    for (int t = tid; t < E; t += 1024) {
        u64 k = bkeys[t];
        int rank = 0;
        for (int j = 0; j < E; ++j) rank += (bkeys[j] > k);   // keys unique (idx distinct)
        if (rank < R) cand[D + rank] = k;
    }
    __syncthreads();

    // bitonic sort descending, 1024 elements
    for (int k = 2; k <= KTOP; k <<= 1) {
        for (int j = k >> 1; j > 0; j >>= 1) {
            int i = tid;
            int ixj = i ^ j;
            if (ixj > i) {
                u64 a_ = cand[i], b_ = cand[ixj];
                bool sw = ((i & k) == 0) ? (a_ < b_) : (a_ > b_);
                if (sw) { cand[i] = b_; cand[ixj] = a_; }
            }
            __syncthreads();
        }
    }

    u64 c = cand[tid];
    top_idx[n * KTOP + tid]   = ~(u32)(c & 0xFFFFFFFFull);
    top_score[n * KTOP + tid] = __uint_as_float((u32)(c >> 32));
}

// ---------------- K5: gather + decode boxes/landmarks ----------------
__global__ void decode_kernel(const float* __restrict__ loc, const float* __restrict__ landms,
                              const float* __restrict__ priors, const u32* __restrict__ top_idx,
                              const float* __restrict__ top_score, float* __restrict__ det) {
    int id = blockIdx.x * blockDim.x + threadIdx.x;
    if (id >= N_IMG * KTOP) return;
    int n = id >> 10;
    u32 a = top_idx[id];
    float4 p = *(const float4*)(priors + (size_t)a * 4);
    float4 l = *(const float4*)(loc + ((size_t)n * NA + a) * 4);

    float cx = p.x + l.x * 0.1f * p.z;
    float cy = p.y + l.y * 0.1f * p.w;
    float w  = p.z * cr_expf(l.z * 0.2f);
    float h  = p.w * cr_expf(l.w * 0.2f);

    float* o = det + (size_t)id * 15;
    o[0] = (cx - w * 0.5f) * IM_F;
    o[1] = (cy - h * 0.5f) * IM_F;
    o[2] = (cx + w * 0.5f) * IM_F;
    o[3] = (cy + h * 0.5f) * IM_F;
    o[4] = top_score[id];

    const float* mp = landms + ((size_t)n * NA + a) * 10;
    #pragma unroll
    for (int q = 0; q < 5; ++q) {
        o[5 + 2 * q]     = (p.x + mp[2 * q]     * 0.1f * p.z) * IM_F;
        o[5 + 2 * q + 1] = (p.y + mp[2 * q + 1] * 0.1f * p.w) * IM_F;
    }
}

// ---------------- K6: IoU suppression bitmask, wave-per-row + ballot ----------
__global__ __launch_bounds__(256) void mask_kernel(const float* __restrict__ det,
                                                   u64* __restrict__ mask) {
    const int n    = blockIdx.x >> 4;        // image
    const int sub  = blockIdx.x & 15;        // block within image
    const int wid  = threadIdx.x >> 6;       // wave in block
    const int lane = threadIdx.x & 63;
    const int q    = sub * 4 + wid;          // wave id within image, 0..63
    const int tid  = threadIdx.x;

    __shared__ float bx1[KTOP], by1[KTOP], bx2[KTOP], by2[KTOP], ba[KTOP];
    for (int j = tid; j < KTOP; j += 256) {
        const float* dr = det + ((size_t)n * KTOP + j) * 15;
        float x1 = dr[0], y1 = dr[1], x2 = dr[2], y2 = dr[3];
        bx1[j] = x1; by1[j] = y1; bx2[j] = x2; by2[j] = y2;
        ba[j] = fmaxf(x2 - x1, 0.f) * fmaxf(y2 - y1, 0.f);
    }
    __syncthreads();

    u64* mbase = mask + (size_t)n * KTOP * 16;
    #pragma unroll 1
    for (int k = 0; k < 16; ++k) {
        const int i = k * 64 + q;
        const float x1i = bx1[i], y1i = by1[i], x2i = bx2[i], y2i = by2[i], ai = ba[i];
        u64* orow = mbase + (size_t)i * 16;
        if (lane < k) orow[lane] = 0ull;               // zero low words
        #pragma unroll 1
        for (int w = k; w < 16; ++w) {
            const int j = w * 64 + lane;
            bool bit = false;
            if (j > i) {
                float xx1 = fmaxf(x1i, bx1[j]);
                float yy1 = fmaxf(y1i, by1[j]);
                float xx2 = fminf(x2i, bx2[j]);
                float yy2 = fminf(y2i, by2[j]);
                float inter = fmaxf(xx2 - xx1, 0.f) * fmaxf(yy2 - yy1, 0.f);
                float iou = inter / (ai + ba[j] - inter + 1e-9f);   // ref formula order
                bit = iou > 0.4f;
            }
            u64 m = __ballot(bit);
            if (lane == 0) orow[w] = m;
        }
    }
}

// ---------------- K7: LDS-staged sequential greedy NMS + fused masked output ----
__global__ __launch_bounds__(1024) void nms_out_kernel(const float* __restrict__ top_score,
                                                       const u64* __restrict__ mask,
                                                       const float* __restrict__ det,
                                                       float* __restrict__ out) {
    const int n = blockIdx.x;
    const int tid = threadIdx.x;
    __shared__ u64 lmask[512 * 16];   // 64 KB: one half of the 1024x1024-bit mask

    const u64* mbase = mask + (size_t)n * KTOP * 16;
    u64 myw = 0;
    if (tid < 64) {
        const int lane = tid;
        for (int g = 0; g < 16; ++g) {
            u64 b = __ballot(top_score[n * KTOP + g * 64 + lane] > 0.5f);
            if (lane == g) myw = b;
        }
    }

    #pragma unroll 1
    for (int half = 0; half < 2; ++half) {
        __syncthreads();   // protect lmask from previous half's readers
        #pragma unroll
        for (int k = 0; k < 8; ++k) {
            int idx = tid + k * 1024;
            lmask[idx] = mbase[(size_t)half * 8192 + idx];
        }
        __syncthreads();
        if (tid < 64) {
            const int lane = tid;
            for (int g = half * 8; g < half * 8 + 8; ++g) {
                u64 kw = readlane64(myw, g);   // group's current keep bits -> SGPR
                const int rbase = (g * 64 - half * 512) * 16;
                #pragma unroll 8
                for (int l = 0; l < 64; ++l) {
                    u64 row = lmask[rbase + l * 16 + (lane & 15)];
                    if ((kw >> l) & 1ull) {
                        kw &= ~readlane64(row, g);       // in-group forward suppress
                        if (lane < 16) myw &= ~row;      // global forward suppress
                    }
                }
            }
        }
    }
    __syncthreads();
    if (tid < 16) lmask[tid] = myw;   // publish keep bits (mask rows no longer needed)
    __syncthreads();

    // masked output write: 15360 floats per image, element-parallel (coalesced)
    const float* drow = det + (size_t)n * KTOP * 15;
    float* orow = out + (size_t)n * KTOP * 15;
    for (int e = tid; e < KTOP * 15; e += 1024) {
        int k = e / 15;
        float f = ((lmask[k >> 6] >> (k & 63)) & 1ull) ? 1.0f : 0.0f;
        orow[e] = drow[e] * f;
    }
}

extern "C" void kernel_launch(void* const* d_in, const int* in_sizes, int n_in,
                              void* d_out, int out_size, void* d_ws, size_t ws_size,
                              hipStream_t stream) {
    const float* loc    = (const float*)d_in[0];
    const float* conf   = (const float*)d_in[1];
    const float* landms = (const float*)d_in[2];
    const float* priors = (const float*)d_in[3];

    char* ws = (char*)d_ws;
    size_t off = 0;
    auto carve = [&](size_t bytes) { void* p = ws + off; off = (off + bytes + 255) & ~255ull; return p; };
    float* scores    = (float*)carve(sizeof(float) * (size_t)N_IMG * NA);
    u32*   top_idx   = (u32*)  carve(sizeof(u32)   * N_IMG * KTOP);
    float* top_score = (float*)carve(sizeof(float) * N_IMG * KTOP);
    float* det       = (float*)carve(sizeof(float) * N_IMG * KTOP * 15);
    u32*   hist      = (u32*)  carve(sizeof(u32)   * (size_t)N_IMG * HBLK * HBIN);  // 4 MB
    u64*   mask      = (u64*)  carve(sizeof(u64)   * (size_t)N_IMG * KTOP * 16);    // 4 MB
    u32*   thr       = (u32*)  carve(sizeof(u32)   * N_IMG);

    score_kernel<<<(N_IMG * NA + 255) / 256, 256, 0, stream>>>((const float2*)conf, scores);
    hist_kernel<<<N_IMG * HBLK, 256, 0, stream>>>(scores, hist);
    thresh_kernel<<<N_IMG, 1024, 0, stream>>>(hist, thr);
    select_kernel<<<N_IMG, 1024, 0, stream>>>(scores, thr, top_idx, top_score);
    decode_kernel<<<(N_IMG * KTOP + 255) / 256, 256, 0, stream>>>(loc, landms, priors, top_idx, top_score, det);
    mask_kernel<<<N_IMG * 16, 256, 0, stream>>>(det, mask);
    nms_out_kernel<<<N_IMG, 1024, 0, stream>>>(top_score, mask, det, (float*)d_out);
}

// Round 6
// 169.599 us; speedup vs baseline: 3.4202x; 1.0410x over previous
//
#include <hip/hip_runtime.h>

typedef unsigned int u32;
typedef unsigned long long u64;

#define N_IMG 32
#define NA 67200
#define KTOP 1024
#define IM_F 1280.0f
#define HBLK 8           // private-histogram blocks per image
#define HBIN 4096        // 12-bit radix of u>>18 (u <= 0x3F7FFFFF -> bin <= 4063)
#define HCHUNK 8400      // NA / HBLK
#define BCAP 6144        // boundary-bin candidate cap (expected ~670)

// Correctly-rounded f32 exp via double (matches any faithful reference exp
// at virtually every point).
__device__ __forceinline__ float cr_expf(float x) { return (float)exp((double)x); }

__device__ __forceinline__ u64 readlane64(u64 v, int lane) {
    u32 lo = (u32)__builtin_amdgcn_readlane((int)(u32)v, lane);
    u32 hi = (u32)__builtin_amdgcn_readlane((int)(u32)(v >> 32), lane);
    return ((u64)hi << 32) | (u64)lo;
}

// ---------------- K1: fused softmax score + private per-block histogram -------
// No global atomics: each block owns a private hist slab (plain stores).
__global__ __launch_bounds__(256) void score_hist_kernel(const float2* __restrict__ conf,
                                                         float* __restrict__ scores,
                                                         u32* __restrict__ hist) {
    const int n   = blockIdx.x >> 3;
    const int blk = blockIdx.x & 7;
    const int tid = threadIdx.x;
    __shared__ u32 h[HBIN];
    for (int i = tid; i < HBIN; i += 256) h[i] = 0;
    __syncthreads();
    const int base = n * NA + blk * HCHUNK;
    for (int a = base + tid; a < base + HCHUNK; a += 256) {
        float2 c = conf[a];
        float m  = fmaxf(c.x, c.y);
        float e0 = cr_expf(c.x - m);   // one of these is exp(0)=1 exactly
        float e1 = cr_expf(c.y - m);
        float s  = e1 / (e0 + e1);
        scores[a] = s;
        atomicAdd(&h[__float_as_uint(s) >> 18], 1u);
    }
    __syncthreads();
    u32* out = hist + ((size_t)n * HBLK + blk) * HBIN;
    for (int i = tid; i < HBIN; i += 256) out[i] = h[i];
}

// ---------------- K2: per-image crossing bin via LDS suffix scan -------------
// B such that GE(B) >= KTOP > GT(B). Only B is needed downstream.
__global__ __launch_bounds__(1024) void thresh_kernel(const u32* __restrict__ hist,
                                                      u32* __restrict__ thr) {
    const int n = blockIdx.x, tid = threadIdx.x;
    __shared__ u32 sA[1024], sB[1024];
    __shared__ u32 res_b;
    const u32* hb = hist + (size_t)n * HBLK * HBIN;
    u32 h0 = 0, h1 = 0, h2 = 0, h3 = 0;
    #pragma unroll
    for (int blk = 0; blk < HBLK; ++blk) {
        const u32* p = hb + blk * HBIN + tid * 4;
        h0 += p[0]; h1 += p[1]; h2 += p[2]; h3 += p[3];
    }
    sA[tid] = h0 + h1 + h2 + h3;
    __syncthreads();
    u32 *src = sA, *dst = sB;
    for (int d = 1; d < 1024; d <<= 1) {
        dst[tid] = src[tid] + ((tid + d < 1024) ? src[tid + d] : 0u);
        __syncthreads();
        u32* t = src; src = dst; dst = t;
    }
    u32 GT3 = (tid + 1 < 1024) ? src[tid + 1] : 0u;   // sum over bins > 4*tid+3
    u32 GE3 = GT3 + h3;
    u32 GE2 = GE3 + h2;
    u32 GE1 = GE2 + h1;
    u32 GE0 = GE1 + h0;
    if (GE3 >= KTOP && GT3 < KTOP) res_b = 4u * tid + 3u;
    if (GE2 >= KTOP && GE3 < KTOP) res_b = 4u * tid + 2u;
    if (GE1 >= KTOP && GE2 < KTOP) res_b = 4u * tid + 1u;
    if (GE0 >= KTOP && GE1 < KTOP) res_b = 4u * tid + 0u;
    __syncthreads();
    if (tid == 0) thr[n] = res_b;
}

// ---------------- K3: exact select (LDS compact + rank-count) + bitonic sort --
// key = (score_bits<<32)|~idx ; desc key == score desc, index asc (lax.top_k ties).
__global__ __launch_bounds__(1024) void select_kernel(const float* __restrict__ scores,
                                                      const u32* __restrict__ thr,
                                                      u32* __restrict__ top_idx,
                                                      float* __restrict__ top_score) {
    const int n = blockIdx.x, tid = threadIdx.x;
    __shared__ u64 cand[KTOP];      // 8 KB
    __shared__ u64 bkeys[BCAP];     // 48 KB
    __shared__ u32 cntd_s, cntb_s;
    if (tid == 0) { cntd_s = 0; cntb_s = 0; }
    __syncthreads();

    const u32 B = thr[n];
    const float* s = scores + (size_t)n * NA;
    for (int a = tid; a < NA; a += 1024) {
        u32 u = __float_as_uint(s[a]);
        u32 b = u >> 18;
        if (b > B) {
            u32 p = atomicAdd(&cntd_s, 1u);           // provably < KTOP
            cand[p] = ((u64)u << 32) | (u32)(~(u32)a);
        } else if (b == B) {
            u32 p = atomicAdd(&cntb_s, 1u);
            if (p < BCAP) bkeys[p] = ((u64)u << 32) | (u32)(~(u32)a);
        }
    }
    __syncthreads();

    const int D = (int)cntd_s;               // == GT(B) < KTOP
    const int R = KTOP - D;                  // take R largest boundary keys
    const int E = min((int)cntb_s, BCAP);    // >= R by construction (GE(B) >= KTOP)
    for (int t = tid; t < E; t += 1024) {
        u64 k = bkeys[t];
        int rank = 0;
        for (int j = 0; j < E; ++j) rank += (bkeys[j] > k);   // keys unique (idx distinct)
        if (rank < R) cand[D + rank] = k;
    }
    __syncthreads();

    // bitonic sort descending, 1024 elements
    for (int k = 2; k <= KTOP; k <<= 1) {
        for (int j = k >> 1; j > 0; j >>= 1) {
            int i = tid;
            int ixj = i ^ j;
            if (ixj > i) {
                u64 a_ = cand[i], b_ = cand[ixj];
                bool sw = ((i & k) == 0) ? (a_ < b_) : (a_ > b_);
                if (sw) { cand[i] = b_; cand[ixj] = a_; }
            }
            __syncthreads();
        }
    }

    u64 c = cand[tid];
    top_idx[n * KTOP + tid]   = ~(u32)(c & 0xFFFFFFFFull);
    top_score[n * KTOP + tid] = __uint_as_float((u32)(c >> 32));
}

// ---------------- K4: gather + decode boxes/landmarks ----------------
__global__ void decode_kernel(const float* __restrict__ loc, const float* __restrict__ landms,
                              const float* __restrict__ priors, const u32* __restrict__ top_idx,
                              const float* __restrict__ top_score, float* __restrict__ det) {
    int id = blockIdx.x * blockDim.x + threadIdx.x;
    if (id >= N_IMG * KTOP) return;
    int n = id >> 10;
    u32 a = top_idx[id];
    float4 p = *(const float4*)(priors + (size_t)a * 4);
    float4 l = *(const float4*)(loc + ((size_t)n * NA + a) * 4);

    float cx = p.x + l.x * 0.1f * p.z;
    float cy = p.y + l.y * 0.1f * p.w;
    float w  = p.z * cr_expf(l.z * 0.2f);
    float h  = p.w * cr_expf(l.w * 0.2f);

    float* o = det + (size_t)id * 15;
    o[0] = (cx - w * 0.5f) * IM_F;
    o[1] = (cy - h * 0.5f) * IM_F;
    o[2] = (cx + w * 0.5f) * IM_F;
    o[3] = (cy + h * 0.5f) * IM_F;
    o[4] = top_score[id];

    const float* mp = landms + ((size_t)n * NA + a) * 10;
    #pragma unroll
    for (int q = 0; q < 5; ++q) {
        o[5 + 2 * q]     = (p.x + mp[2 * q]     * 0.1f * p.z) * IM_F;
        o[5 + 2 * q + 1] = (p.y + mp[2 * q + 1] * 0.1f * p.w) * IM_F;
    }
}

// ---------------- K5: IoU suppression bitmask, wave-per-row + ballot ----------
__global__ __launch_bounds__(256) void mask_kernel(const float* __restrict__ det,
                                                   u64* __restrict__ mask) {
    const int n    = blockIdx.x >> 4;        // image
    const int sub  = blockIdx.x & 15;        // block within image
    const int wid  = threadIdx.x >> 6;       // wave in block
    const int lane = threadIdx.x & 63;
    const int q    = sub * 4 + wid;          // wave id within image, 0..63
    const int tid  = threadIdx.x;

    __shared__ float bx1[KTOP], by1[KTOP], bx2[KTOP], by2[KTOP], ba[KTOP];
    for (int j = tid; j < KTOP; j += 256) {
        const float* dr = det + ((size_t)n * KTOP + j) * 15;
        float x1 = dr[0], y1 = dr[1], x2 = dr[2], y2 = dr[3];
        bx1[j] = x1; by1[j] = y1; bx2[j] = x2; by2[j] = y2;
        ba[j] = fmaxf(x2 - x1, 0.f) * fmaxf(y2 - y1, 0.f);
    }
    __syncthreads();

    u64* mbase = mask + (size_t)n * KTOP * 16;
    #pragma unroll 1
    for (int k = 0; k < 16; ++k) {
        const int i = k * 64 + q;
        const float x1i = bx1[i], y1i = by1[i], x2i = bx2[i], y2i = by2[i], ai = ba[i];
        u64* orow = mbase + (size_t)i * 16;
        if (lane < k) orow[lane] = 0ull;               // zero low words
        #pragma unroll 1
        for (int w = k; w < 16; ++w) {
            const int j = w * 64 + lane;
            bool bit = false;
            if (j > i) {
                float xx1 = fmaxf(x1i, bx1[j]);
                float yy1 = fmaxf(y1i, by1[j]);
                float xx2 = fminf(x2i, bx2[j]);
                float yy2 = fminf(y2i, by2[j]);
                float inter = fmaxf(xx2 - xx1, 0.f) * fmaxf(yy2 - yy1, 0.f);
                float iou = inter / (ai + ba[j] - inter + 1e-9f);   // ref formula order
                bit = iou > 0.4f;
            }
            u64 m = __ballot(bit);
            if (lane == 0) orow[w] = m;
        }
    }
}

// ---------------- K6: LDS-staged sequential greedy NMS + fused masked output ----
// Serial loop is software-pipelined: row l+1 is loaded from LDS before row l is
// consumed, so the LDS latency never sits on the serial chain. The suppression
// update is branch-free across lanes (lanes >=16 hold garbage myw, never read);
// the only branch is the wave-uniform kept-bit test.
__global__ __launch_bounds__(1024) void nms_out_kernel(const float* __restrict__ top_score,
                                                       const u64* __restrict__ mask,
                                                       const float* __restrict__ det,
                                                       float* __restrict__ out) {
    const int n = blockIdx.x;
    const int tid = threadIdx.x;
    __shared__ u64 lmask[512 * 16];   // 64 KB: one half of the 1024x1024-bit mask

    const u64* mbase = mask + (size_t)n * KTOP * 16;
    u64 myw = 0;
    if (tid < 64) {
        const int lane = tid;
        for (int g = 0; g < 16; ++g) {
            u64 b = __ballot(top_score[n * KTOP + g * 64 + lane] > 0.5f);
            if (lane == g) myw = b;
        }
    }

    #pragma unroll 1
    for (int half = 0; half < 2; ++half) {
        __syncthreads();   // protect lmask from previous half's readers
        #pragma unroll
        for (int k = 0; k < 8; ++k) {
            int idx = tid + k * 1024;
            lmask[idx] = mbase[(size_t)half * 8192 + idx];
        }
        __syncthreads();
        if (tid < 64) {
            const int l16 = tid & 15;
            int lr = 0;                       // local row within this half
            u64 nxt = lmask[l16];             // prefetch row 0
            #pragma unroll 1
            for (int g = half * 8; g < half * 8 + 8; ++g) {
                u64 kw = readlane64(myw, g);  // group's current keep bits -> SGPR
                #pragma unroll 4
                for (int l = 0; l < 64; ++l) {
                    u64 row = nxt;
                    int nlr = (lr + 1 < 512) ? lr + 1 : 511;
                    nxt = lmask[nlr * 16 + l16];          // prefetch next row
                    ++lr;
                    if ((kw >> l) & 1ull) {               // wave-uniform branch
                        kw &= ~readlane64(row, g);        // in-group forward suppress
                        myw &= ~row;                      // all lanes; only 0..15 read
                    }
                }
            }
        }
    }
    __syncthreads();
    if (tid < 16) lmask[tid] = myw;   // publish keep bits (mask rows no longer needed)
    __syncthreads();

    // masked output write: 15360 floats per image, element-parallel (coalesced)
    const float* drow = det + (size_t)n * KTOP * 15;
    float* orow = out + (size_t)n * KTOP * 15;
    for (int e = tid; e < KTOP * 15; e += 1024) {
        int k = e / 15;
        float f = ((lmask[k >> 6] >> (k & 63)) & 1ull) ? 1.0f : 0.0f;
        orow[e] = drow[e] * f;
    }
}

extern "C" void kernel_launch(void* const* d_in, const int* in_sizes, int n_in,
                              void* d_out, int out_size, void* d_ws, size_t ws_size,
                              hipStream_t stream) {
    const float* loc    = (const float*)d_in[0];
    const float* conf   = (const float*)d_in[1];
    const float* landms = (const float*)d_in[2];
    const float* priors = (const float*)d_in[3];

    char* ws = (char*)d_ws;
    size_t off = 0;
    auto carve = [&](size_t bytes) { void* p = ws + off; off = (off + bytes + 255) & ~255ull; return p; };
    float* scores    = (float*)carve(sizeof(float) * (size_t)N_IMG * NA);
    u32*   top_idx   = (u32*)  carve(sizeof(u32)   * N_IMG * KTOP);
    float* top_score = (float*)carve(sizeof(float) * N_IMG * KTOP);
    float* det       = (float*)carve(sizeof(float) * N_IMG * KTOP * 15);
    u32*   hist      = (u32*)  carve(sizeof(u32)   * (size_t)N_IMG * HBLK * HBIN);  // 4 MB
    u64*   mask      = (u64*)  carve(sizeof(u64)   * (size_t)N_IMG * KTOP * 16);    // 4 MB
    u32*   thr       = (u32*)  carve(sizeof(u32)   * N_IMG);

    score_hist_kernel<<<N_IMG * HBLK, 256, 0, stream>>>((const float2*)conf, scores, hist);
    thresh_kernel<<<N_IMG, 1024, 0, stream>>>(hist, thr);
    select_kernel<<<N_IMG, 1024, 0, stream>>>(scores, thr, top_idx, top_score);
    decode_kernel<<<(N_IMG * KTOP + 255) / 256, 256, 0, stream>>>(loc, landms, priors, top_idx, top_score, det);
    mask_kernel<<<N_IMG * 16, 256, 0, stream>>>(det, mask);
    nms_out_kernel<<<N_IMG, 1024, 0, stream>>>(top_score, mask, det, (float*)d_out);
}